// Round 7
// baseline (818.106 us; speedup 1.0000x reference)
//
#include <hip/hip_runtime.h>
#include <hip/hip_bf16.h>
#include <hip/hip_cooperative_groups.h>
#include <cstdint>

namespace cg = cooperative_groups;

#define N_NODES   50000
#define FEAT      128
#define OUTF      256
#define MAX_EDGES 800000
#define INV_SQRT3 0.57735026918962576f
#define NW        (64 + 64*64 + 64*128)          // 12,352 weights
#define PREP_BLOCKS 1024
#define GSIZE     (PREP_BLOCKS * 256)            // 262,144 threads

// All scratch in device globals; d_ws untouched.
__device__ float g_wf[NW];
__device__ float g_lut[65536 * 128];             // 32 MB mix LUT (float4-interleaved per channel)
__device__ int   g_flags[8];                     // [0] snd i64, [1] rcv i64, [2] nf bf16, [3] ea bf16, [4..6] w bf16
__device__ int   g_cnt[N_NODES];
__device__ int   g_rowstart[N_NODES + 1];
__device__ int   g_pos[N_NODES];
__device__ int   g_bsum[256];
__device__ uint4 g_rec[MAX_EDGES];               // {si, b0, e1x|e1y<<16, e1z} receiver-sorted
__device__ unsigned char g_used[65536];
__device__ int   g_used_list[65536];
__device__ int   g_nused;

__device__ __forceinline__ float b2f(uint32_t b) {
    union { uint32_t u; float f; } v; v.u = b << 16; return v.f;
}
__device__ __forceinline__ uint32_t f2b_bits(float f) {
    union { float f; uint32_t u; } v; v.f = f;
    uint32_t u = v.u;
    u += 0x7fffu + ((u >> 16) & 1u);
    return u >> 16;
}
__device__ __forceinline__ float swishf(float x) {
    return x / (1.0f + __expf(-x));
}
__device__ __forceinline__ float sane(float x) {   // |x|>=2^14 / inf / NaN -> 0 (integer-domain)
    union { float f; uint32_t u; } v; v.f = x;
    return (((v.u >> 23) & 0xffu) >= 0x8Du) ? 0.0f : x;
}
__device__ __forceinline__ float loadf(const void* p, int i, int isbf) {
    return isbf ? b2f(((const uint16_t*)p)[i]) : ((const float*)p)[i];
}

// ================= cooperative prep: probes, hist, scan, scatter, LUT =================
__global__ __launch_bounds__(256, 4) void prep_kernel(
    const void* nf, const void* ea, const void* w0, const void* w1, const void* w2,
    const int* snd, const int* rcv, int snd_force64, int n_edges)
{
    cg::grid_group grid = cg::this_grid();
    const int tid = threadIdx.x;
    const int gtid = blockIdx.x * 256 + tid;
    __shared__ int sh[256];

    // ---- phase 0: dtype probes (block 0) + zero counters (all blocks) ----
    if (blockIdx.x == 0) {
        __shared__ int viol[7];
        if (tid < 7) viol[tid] = 0;
        __syncthreads();
        const void* ptrs[5] = { nf, ea, w0, w1, w2 };
        const int ns[5] = { N_NODES * FEAT, n_edges * 4, 64, 4096, 8192 };
        #pragma unroll
        for (int q = 0; q < 5; ++q) {
            int n = ns[q];
            int step = (n / 256) | 1;
            long long i = (long long)tid * step;
            if (i < n) {
                uint32_t e = (((const uint16_t*)ptrs[q])[i] >> 7) & 0xffu;
                if (e > 140u) atomicOr(&viol[q + 2], 1);
            }
        }
        if (tid < 64) {
            int i = 2 * tid + 1;
            if (i < 2 * n_edges) {
                if (snd[i] != 0) atomicOr(&viol[0], 1);
                if (rcv[i] != 0) atomicOr(&viol[1], 1);
            }
        }
        __syncthreads();
        if (tid == 0) {
            g_flags[0] = snd_force64 ? 1 : !viol[0];
            g_flags[1] = !viol[1];
            g_flags[2] = !viol[2];
            g_flags[3] = !viol[3];
            g_flags[4] = !viol[4];
            g_flags[5] = !viol[5];
            g_flags[6] = !viol[6];
        }
    }
    if (gtid < N_NODES) g_cnt[gtid] = 0;
    if (gtid < 16384)   ((int*)g_used)[gtid] = 0;
    if (gtid == 0)      g_nused = 0;
    grid.sync();

    const int f1 = g_flags[1], f3 = g_flags[3];
    // ---- phase 1: histogram + used-pattern marking + weight convert ----
    for (int e = gtid; e < n_edges; e += GSIZE) {
        int ri = f1 ? rcv[2 * e] : rcv[e];
        ri = min(max(ri, 0), N_NODES - 1);
        atomicAdd(&g_cnt[ri], 1);
        uint32_t b0 = f3 ? (uint32_t)((const uint16_t*)ea)[4 * e]
                         : f2b_bits(((const float*)ea)[4 * e]);
        g_used[b0 & 0xffffu] = 1;
    }
    if (gtid < 64)             g_wf[gtid] = loadf(w0, gtid, g_flags[4]);
    else if (gtid < 64 + 4096) g_wf[gtid] = loadf(w1, gtid - 64, g_flags[5]);
    else if (gtid < NW)        g_wf[gtid] = loadf(w2, gtid - (64 + 4096), g_flags[6]);
    grid.sync();

    // ---- phase 2a: per-block (256-wide) scan of counts; blocks 0..195 ----
    if (blockIdx.x < 196) {
        int i = blockIdx.x * 256 + tid;
        int v = (i < N_NODES) ? g_cnt[i] : 0;
        sh[tid] = v;
        __syncthreads();
        for (int d = 1; d < 256; d <<= 1) {
            int x = (tid >= d) ? sh[tid - d] : 0;
            __syncthreads();
            sh[tid] += x;
            __syncthreads();
        }
        if (i < N_NODES) g_rowstart[i] = sh[tid] - v;   // exclusive (local)
        if (tid == 255)  g_bsum[blockIdx.x] = sh[255];
    }
    grid.sync();
    // ---- phase 2b: block 0 scans the 196 block sums ----
    if (blockIdx.x == 0) {
        int v = (tid < 196) ? g_bsum[tid] : 0;
        sh[tid] = v;
        __syncthreads();
        for (int d = 1; d < 256; d <<= 1) {
            int x = (tid >= d) ? sh[tid - d] : 0;
            __syncthreads();
            sh[tid] += x;
            __syncthreads();
        }
        if (tid < 196) g_bsum[tid] = sh[tid] - v;       // exclusive
    }
    grid.sync();
    // ---- phase 2c: add block offsets; init write cursors; compact used list ----
    if (blockIdx.x < 196) {
        int i = blockIdx.x * 256 + tid;
        if (i < N_NODES) {
            int v = g_rowstart[i] + g_bsum[blockIdx.x];
            g_rowstart[i] = v;
            g_pos[i] = v;
        }
    }
    if (gtid == 0) g_rowstart[N_NODES] = n_edges;
    if (gtid < 65536 && g_used[gtid]) {
        int p = atomicAdd(&g_nused, 1);
        g_used_list[p] = gtid;
    }
    grid.sync();

    // ---- phase 3a: scatter packed edge records into receiver order ----
    const int f0 = g_flags[0];
    for (int e = gtid; e < n_edges; e += GSIZE) {
        int ri = f1 ? rcv[2 * e] : rcv[e];
        ri = min(max(ri, 0), N_NODES - 1);
        int si = f0 ? snd[2 * e] : snd[e];
        si = min(max(si, 0), N_NODES - 1);
        uint32_t b0, xy, z;
        if (f3) {
            uint2 w = ((const uint2*)ea)[e];
            b0 = w.x & 0xffffu;
            xy = (w.x >> 16) | (w.y << 16);     // e1x | e1y<<16
            z  = w.y >> 16;                      // e1z
        } else {
            float4 w = ((const float4*)ea)[e];
            b0 = f2b_bits(w.x) & 0xffffu;
            xy = f2b_bits(w.y) | (f2b_bits(w.z) << 16);
            z  = f2b_bits(w.w);
        }
        int p = atomicAdd(&g_pos[ri], 1);
        if (p < MAX_EDGES) g_rec[p] = make_uint4((uint32_t)si, b0, xy, z);
    }
    // ---- phase 3b: wave-parallel LUT build (float4-interleaved layout) ----
    {
        int wave0 = gtid >> 6;
        int lane = tid & 63;
        int nwaves = GSIZE >> 6;                 // 4096
        int nused = g_nused;
        const float* w1p = g_wf + 64;
        const float* w2p = g_wf + 64 + 4096;
        float w0l = g_wf[lane];
        int li = lane & 31, hi = lane >> 5;
        float sA = hi ? (0.03125f * INV_SQRT3) : 0.03125f;  // m1 gets INV_SQRT3
        for (int w = wave0; w < nused; w += nwaves) {
            int r = g_used_list[w];
            float x = b2f((uint32_t)r);
            float h0 = swishf(x * w0l);
            float a = 0.f;
            #pragma unroll 8
            for (int k = 0; k < 64; ++k)
                a += __shfl(h0, k, 64) * w1p[k * 64 + lane];
            float h1 = swishf(a * 0.125f);
            float a0 = 0.f, a1 = 0.f;
            #pragma unroll 8
            for (int k = 0; k < 64; ++k) {
                float h1k = __shfl(h1, k, 64);
                a0 += h1k * w2p[k * 128 + lane];
                a1 += h1k * w2p[k * 128 + 64 + lane];
            }
            // old ch lane -> {m0 ch li | m1 ch li}; old ch 64+lane -> {m2 | m3}
            float* dst = g_lut + ((size_t)r << 7);
            dst[(li << 2) + hi]     = sane(a0 * sA);
            dst[(li << 2) + 2 + hi] = sane(a1 * 0.03125f);
        }
    }
}

// ================= gather v3: packed records, float4 LUT, dword nf loads =================
__global__ __launch_bounds__(256) void gather_kernel(
    const void* __restrict__ nf, void* __restrict__ out)
{
    int wid = (blockIdx.x * 256 + threadIdx.x) >> 6;
    int lane = threadIdx.x & 63;
    if (wid >= N_NODES) return;
    int c = lane & 31;
    int half = lane >> 5;
    const int f2 = g_flags[2];
    int k0 = g_rowstart[wid], k1 = g_rowstart[wid + 1];
    int deg = k1 - k0;

    float o0 = 0.f, o1 = 0.f, o2 = 0.f, o3 = 0.f,
          o4 = 0.f, o5 = 0.f, o6 = 0.f, o7 = 0.f;

    for (int base = 0; base < deg; base += 64) {
        int nchunk = min(64, deg - base);
        uint4 r = make_uint4(0u, 0u, 0u, 0u);
        if (lane < nchunk) r = g_rec[k0 + base + lane];   // one coalesced 16B load
        int pairs = nchunk & ~1;

        #pragma unroll 2
        for (int j = 0; j < pairs; j += 2) {
            int jj = j + half;
            int      si = __shfl((int)r.x, jj, 64);
            uint32_t b0 = (uint32_t)__shfl((int)r.y, jj, 64);
            uint32_t xy = (uint32_t)__shfl((int)r.z, jj, 64);
            uint32_t zb = (uint32_t)__shfl((int)r.w, jj, 64);

            float4 mv = *(const float4*)(g_lut + ((size_t)b0 << 7) + (c << 2));
            float e1x = b2f(xy & 0xffffu), e1y = b2f(xy >> 16), e1z = b2f(zb);
            float s, v0, v1, v2;
            if (f2) {
                const uint16_t* row = (const uint16_t*)nf + ((size_t)si << 7);
                s = b2f(row[c]);
                const uint32_t* r32 = (const uint32_t*)row;
                int d = (64 + 6 * c) >> 2;
                uint32_t u0 = r32[d], u1 = r32[d + 1];
                uint32_t q = c & 1;
                uint32_t w0_ = q ? ((u0 >> 16) | (u1 << 16)) : u0;
                v0 = b2f(w0_ & 0xffffu); v1 = b2f(w0_ >> 16);
                v2 = b2f(q ? (u1 >> 16) : (u1 & 0xffffu));
            } else {
                const float* row = (const float*)nf + ((size_t)si << 7);
                s  = row[c];
                v0 = row[32 + 3 * c + 0];
                v1 = row[32 + 3 * c + 1];
                v2 = row[32 + 3 * c + 2];
            }
            o0 += s * mv.x;
            o1 += (v0 * e1x + v1 * e1y + v2 * e1z) * mv.y;
            o2 += v0 * mv.z; o3 += v1 * mv.z; o4 += v2 * mv.z;
            float sm3 = s * mv.w;
            o5 += e1x * sm3; o6 += e1y * sm3; o7 += e1z * sm3;
        }

        if (pairs < nchunk) {                     // odd tail: half 0 contributes, half 1 gated
            int jj = pairs;
            float wgt = (half == 0) ? 1.0f : 0.0f;
            int      si = __shfl((int)r.x, jj, 64);
            uint32_t b0 = (uint32_t)__shfl((int)r.y, jj, 64);
            uint32_t xy = (uint32_t)__shfl((int)r.z, jj, 64);
            uint32_t zb = (uint32_t)__shfl((int)r.w, jj, 64);

            float4 mv = *(const float4*)(g_lut + ((size_t)b0 << 7) + (c << 2));
            float m0 = mv.x * wgt, m1 = mv.y * wgt, m2 = mv.z * wgt, m3 = mv.w * wgt;
            float e1x = b2f(xy & 0xffffu), e1y = b2f(xy >> 16), e1z = b2f(zb);
            float s, v0, v1, v2;
            if (f2) {
                const uint16_t* row = (const uint16_t*)nf + ((size_t)si << 7);
                s = b2f(row[c]);
                const uint32_t* r32 = (const uint32_t*)row;
                int d = (64 + 6 * c) >> 2;
                uint32_t u0 = r32[d], u1 = r32[d + 1];
                uint32_t q = c & 1;
                uint32_t w0_ = q ? ((u0 >> 16) | (u1 << 16)) : u0;
                v0 = b2f(w0_ & 0xffffu); v1 = b2f(w0_ >> 16);
                v2 = b2f(q ? (u1 >> 16) : (u1 & 0xffffu));
            } else {
                const float* row = (const float*)nf + ((size_t)si << 7);
                s  = row[c];
                v0 = row[32 + 3 * c + 0];
                v1 = row[32 + 3 * c + 1];
                v2 = row[32 + 3 * c + 2];
            }
            o0 += s * m0;
            o1 += (v0 * e1x + v1 * e1y + v2 * e1z) * m1;
            o2 += v0 * m2; o3 += v1 * m2; o4 += v2 * m2;
            float sm3 = s * m3;
            o5 += e1x * sm3; o6 += e1y * sm3; o7 += e1z * sm3;
        }
    }

    o0 += __shfl_xor(o0, 32, 64);
    o1 += __shfl_xor(o1, 32, 64);
    o2 += __shfl_xor(o2, 32, 64);
    o3 += __shfl_xor(o3, 32, 64);
    o4 += __shfl_xor(o4, 32, 64);
    o5 += __shfl_xor(o5, 32, 64);
    o6 += __shfl_xor(o6, 32, 64);
    o7 += __shfl_xor(o7, 32, 64);

    if (half == 0) {
        size_t bo = (size_t)wid * OUTF;
        if (f2) {
            uint16_t* o = (uint16_t*)out;
            o[bo + c]              = (uint16_t)f2b_bits(o0);
            o[bo + 32 + c]         = (uint16_t)f2b_bits(o1);
            o[bo + 64 + 3*c + 0]   = (uint16_t)f2b_bits(o2);
            o[bo + 64 + 3*c + 1]   = (uint16_t)f2b_bits(o3);
            o[bo + 64 + 3*c + 2]   = (uint16_t)f2b_bits(o4);
            o[bo + 160 + 3*c + 0]  = (uint16_t)f2b_bits(o5);
            o[bo + 160 + 3*c + 1]  = (uint16_t)f2b_bits(o6);
            o[bo + 160 + 3*c + 2]  = (uint16_t)f2b_bits(o7);
        } else {
            float* o = (float*)out;
            o[bo + c]              = o0;
            o[bo + 32 + c]         = o1;
            o[bo + 64 + 3*c + 0]   = o2;
            o[bo + 64 + 3*c + 1]   = o3;
            o[bo + 64 + 3*c + 2]   = o4;
            o[bo + 160 + 3*c + 0]  = o5;
            o[bo + 160 + 3*c + 1]  = o6;
            o[bo + 160 + 3*c + 2]  = o7;
        }
    }
}

extern "C" void kernel_launch(void* const* d_in, const int* in_sizes, int n_in,
                              void* d_out, int out_size, void* d_ws, size_t ws_size,
                              hipStream_t stream) {
    (void)n_in; (void)out_size; (void)d_ws; (void)ws_size;
    const void* nf = d_in[0];
    const void* ea = d_in[1];
    const int* snd = (const int*)d_in[2];
    const int* rcv = (const int*)d_in[3];
    const void* w0 = d_in[4];
    const void* w1 = d_in[5];
    const void* w2 = d_in[6];

    int n_edges = in_sizes[1] / 4;               // edge_attrs is (E,4), dtype-independent
    if (n_edges > MAX_EDGES) n_edges = MAX_EDGES;
    int snd_force64 = (in_sizes[2] == 2 * in_sizes[3]) ? 1 : 0;

    void* kargs[] = { (void*)&nf, (void*)&ea, (void*)&w0, (void*)&w1, (void*)&w2,
                      (void*)&snd, (void*)&rcv, (void*)&snd_force64, (void*)&n_edges };
    hipLaunchCooperativeKernel((const void*)prep_kernel, dim3(PREP_BLOCKS), dim3(256),
                               kargs, 0, stream);
    gather_kernel<<<(N_NODES * 64 + 255) / 256, 256, 0, stream>>>(nf, d_out);
}